// Round 5
// baseline (228.951 us; speedup 1.0000x reference)
//
#include <hip/hip_runtime.h>

// out[t, j] = W[j, x[t]] + b[j]
//   x : [16384] int32, W : [1024, 50257] f32 row-major, b : [1024] f32
//   out: [16384, 1024] f32
//
// R2 (sorted per-token gather, 104us): latency-bound — 4 outstanding
// divergent loads/wave at ~600cyc => ~0.17 trans/cyc/CU.
// R3 (LDS bucket inversion, 118us): regression — barriers + serial serve.
// R4: sorted order + 8 tokens/block, register-only. Each thread issues all
// 32 loads (4 j x 8 tokens) before consuming: 8x MLP, and sorted-adjacent
// tokens sharing a 64B line (~5.2/bucket) are re-read by the SAME thread
// back-to-back -> L1/MSHR merge. v packed into order => no dependent x[t]
// load. No LDS, no barriers.
// (Round 5 = resubmit of round 4: container died, no bench data.)

#define VOCAB 50257
#define DIM   1024
#define NBUCK ((VOCAB + 15) >> 4)     // 3142 line-groups
#define NXCD  8
#define TPB_TOK 8                     // tokens per block

// ---------- sort pipeline (counting sort by v>>4) ----------

__global__ void zero_counts_kernel(int* __restrict__ counts, int n) {
    int i = blockIdx.x * blockDim.x + threadIdx.x;
    if (i < n) counts[i] = 0;
}

__global__ void hist_kernel(const int* __restrict__ x, int n, int* __restrict__ counts) {
    int i = blockIdx.x * blockDim.x + threadIdx.x;
    if (i < n) atomicAdd(&counts[x[i] >> 4], 1);
}

// single block, 256 threads: exclusive prefix sum over NBUCK counters
__global__ __launch_bounds__(256) void scan_kernel(const int* __restrict__ counts,
                                                   int* __restrict__ offs) {
    const int CHUNK = (NBUCK + 255) / 256;   // 13
    __shared__ int lds[256];
    const int tid = threadIdx.x;
    const int base = tid * CHUNK;
    int local[CHUNK];
    int s = 0;
#pragma unroll
    for (int k = 0; k < CHUNK; ++k) {
        int idx = base + k;
        int c = (idx < NBUCK) ? counts[idx] : 0;
        local[k] = s;
        s += c;
    }
    lds[tid] = s;
    __syncthreads();
    if (tid == 0) {
        int run = 0;
        for (int i = 0; i < 256; ++i) { int c = lds[i]; lds[i] = run; run += c; }
    }
    __syncthreads();
    const int boff = lds[tid];
#pragma unroll
    for (int k = 0; k < CHUNK; ++k) {
        int idx = base + k;
        if (idx < NBUCK) offs[idx] = boff + local[k];
    }
}

// offs consumed as running cursors (recomputed every call -> deterministic
// OUTPUT: intra-bucket order varies but out[t] depends only on t's own v).
// Packs (v << 16) | t  — v < 65536, t < 65536.
__global__ void scatter_kernel(const int* __restrict__ x, int n,
                               int* __restrict__ offs, int* __restrict__ order) {
    int i = blockIdx.x * blockDim.x + threadIdx.x;
    if (i < n) {
        int v = x[i];
        int pos = atomicAdd(&offs[v >> 4], 1);
        order[pos] = (v << 16) | i;
    }
}

// ---------- gather: 8 sorted tokens per block, register-only ----------
__global__ __launch_bounds__(256) void gather_mt_kernel(
    const float* __restrict__ W,
    const float* __restrict__ bias,
    const int* __restrict__ order,
    float* __restrict__ out,
    int n, int q, int r)   // q = nblk/8, r = nblk%8
{
    // bijective XCD chunking: round-robin hw blocks -> contiguous sorted ranges
    const int bid = blockIdx.x;
    const int xcd = bid & (NXCD - 1);
    const int idx = bid >> 3;
    const int chunk_base = (xcd < r) ? xcd * (q + 1) : r * (q + 1) + (xcd - r) * q;
    const int t0 = (chunk_base + idx) * TPB_TOK;

    const int j0 = threadIdx.x * 4;
    const float4 bb = *reinterpret_cast<const float4*>(bias + j0);

    const int cnt = min(TPB_TOK, n - t0);

    int pk[TPB_TOK];
#pragma unroll
    for (int k = 0; k < TPB_TOK; ++k)
        pk[k] = order[t0 + ((k < cnt) ? k : 0)];   // uniform -> scalar loads

    // issue all 32 loads before any use: deep MLP + same-line L1 reuse
    float4 r4[TPB_TOK];
#pragma unroll
    for (int k = 0; k < TPB_TOK; ++k) {
        const int v = ((unsigned)pk[k]) >> 16;
        const float* col = W + v;
        r4[k].x = col[(size_t)(j0 + 0) * VOCAB];
        r4[k].y = col[(size_t)(j0 + 1) * VOCAB];
        r4[k].z = col[(size_t)(j0 + 2) * VOCAB];
        r4[k].w = col[(size_t)(j0 + 3) * VOCAB];
    }

#pragma unroll
    for (int k = 0; k < TPB_TOK; ++k) {
        if (k < cnt) {
            const int t = pk[k] & 0xFFFF;
            float4 rr = r4[k];
            rr.x += bb.x; rr.y += bb.y; rr.z += bb.z; rr.w += bb.w;
            *reinterpret_cast<float4*>(out + (size_t)t * DIM + j0) = rr;
        }
    }
}

// fallback (round-1 kernel) if workspace too small / n too large for packing
__global__ __launch_bounds__(256) void gather_direct_kernel(
    const int* __restrict__ x,
    const float* __restrict__ W,
    const float* __restrict__ bias,
    float* __restrict__ out)
{
    const int t = blockIdx.x;
    const int v = x[t];
    const int j0 = threadIdx.x * 4;
    float4 rr;
    rr.x = W[(size_t)(j0 + 0) * VOCAB + v];
    rr.y = W[(size_t)(j0 + 1) * VOCAB + v];
    rr.z = W[(size_t)(j0 + 2) * VOCAB + v];
    rr.w = W[(size_t)(j0 + 3) * VOCAB + v];
    const float4 bb = *reinterpret_cast<const float4*>(bias + j0);
    rr.x += bb.x; rr.y += bb.y; rr.z += bb.z; rr.w += bb.w;
    *reinterpret_cast<float4*>(out + (size_t)t * DIM + j0) = rr;
}

extern "C" void kernel_launch(void* const* d_in, const int* in_sizes, int n_in,
                              void* d_out, int out_size, void* d_ws, size_t ws_size,
                              hipStream_t stream) {
    const int*   x    = (const int*)d_in[0];
    const float* W    = (const float*)d_in[1];
    const float* bias = (const float*)d_in[2];
    float*       out  = (float*)d_out;

    const int n = in_sizes[0];           // 16384 tokens

    const size_t need = (size_t)(2 * NBUCK + n) * sizeof(int);
    if (ws_size < need || n > 65536) {   // packing uses 16 bits for token id
        gather_direct_kernel<<<n, 256, 0, stream>>>(x, W, bias, out);
        return;
    }

    int* counts = (int*)d_ws;            // [NBUCK]
    int* offs   = counts + NBUCK;        // [NBUCK]
    int* order  = offs + NBUCK;          // [n] packed (v<<16 | t)

    const int tb = 256;
    zero_counts_kernel<<<(NBUCK + tb - 1) / tb, tb, 0, stream>>>(counts, NBUCK);
    hist_kernel<<<(n + tb - 1) / tb, tb, 0, stream>>>(x, n, counts);
    scan_kernel<<<1, tb, 0, stream>>>(counts, offs);
    scatter_kernel<<<(n + tb - 1) / tb, tb, 0, stream>>>(x, n, offs, order);

    const int nblk = (n + TPB_TOK - 1) / TPB_TOK;   // 2048
    const int q = nblk / NXCD, r = nblk % NXCD;
    gather_mt_kernel<<<nblk, 256, 0, stream>>>(W, bias, order, out, n, q, r);
}

// Round 6
// 103.657 us; speedup vs baseline: 2.2087x; 2.2087x over previous
//
#include <hip/hip_runtime.h>

// out[t, j] = W[j, x[t]] + b[j]
//   x : [16384] int32, W : [1024, 50257] f32 row-major, b : [1024] f32
//   out: [16384, 1024] f32
//
// R2 (sorted, 1 token/block, 4 loads/thread): 104us, FETCH 102MB, latency-
//    bound (~100 outstanding divergent transactions per CU).
// R4/R5 (8 tokens/block): REGRESSION 229us, FETCH 660MB. VGPR_Count=12
//    proved the compiler sank the 32 loads (no MLP), and the 2048-block
//    grid destroyed the time-ordered sorted sweep (L3 thrash).
// R6: R2's grid/sweep exactly (16384 blocks, XCD-chunked sorted order),
//    but 128 threads/block x 8 j-loads per thread: 2x outstanding per
//    wave, 16 blocks/CU. sched_barrier(0) pins all 8 loads before uses.
//    v packed into order => no dependent x[t] load.

#define VOCAB 50257
#define DIM   1024
#define NBUCK ((VOCAB + 15) >> 4)     // 3142 line-groups
#define NXCD  8

// ---------- sort pipeline (counting sort by v>>4) ----------

__global__ void zero_counts_kernel(int* __restrict__ counts, int n) {
    int i = blockIdx.x * blockDim.x + threadIdx.x;
    if (i < n) counts[i] = 0;
}

__global__ void hist_kernel(const int* __restrict__ x, int n, int* __restrict__ counts) {
    int i = blockIdx.x * blockDim.x + threadIdx.x;
    if (i < n) atomicAdd(&counts[x[i] >> 4], 1);
}

// single block, 256 threads: exclusive prefix sum over NBUCK counters
__global__ __launch_bounds__(256) void scan_kernel(const int* __restrict__ counts,
                                                   int* __restrict__ offs) {
    const int CHUNK = (NBUCK + 255) / 256;   // 13
    __shared__ int lds[256];
    const int tid = threadIdx.x;
    const int base = tid * CHUNK;
    int local[CHUNK];
    int s = 0;
#pragma unroll
    for (int k = 0; k < CHUNK; ++k) {
        int idx = base + k;
        int c = (idx < NBUCK) ? counts[idx] : 0;
        local[k] = s;
        s += c;
    }
    lds[tid] = s;
    __syncthreads();
    if (tid == 0) {
        int run = 0;
        for (int i = 0; i < 256; ++i) { int c = lds[i]; lds[i] = run; run += c; }
    }
    __syncthreads();
    const int boff = lds[tid];
#pragma unroll
    for (int k = 0; k < CHUNK; ++k) {
        int idx = base + k;
        if (idx < NBUCK) offs[idx] = boff + local[k];
    }
}

// offs consumed as running cursors (recomputed every call). Intra-bucket
// order is nondeterministic but out[t] depends only on t's own v ->
// deterministic OUTPUT. Packs (v << 16) | t : v < 65536, t < 65536.
__global__ void scatter_kernel(const int* __restrict__ x, int n,
                               int* __restrict__ offs, int* __restrict__ order) {
    int i = blockIdx.x * blockDim.x + threadIdx.x;
    if (i < n) {
        int v = x[i];
        int pos = atomicAdd(&offs[v >> 4], 1);
        order[pos] = (v << 16) | i;
    }
}

// ---------- gather: 1 sorted token per block, 128 thr x 8 j-loads ----------
__global__ __launch_bounds__(128) void gather_sorted8_kernel(
    const float* __restrict__ W,
    const float* __restrict__ bias,
    const int* __restrict__ order,
    float* __restrict__ out,
    int q, int r)   // q = n/8, r = n%8
{
    // bijective XCD chunking: round-robin hw blocks -> contiguous sorted ranges
    const int bid = blockIdx.x;
    const int xcd = bid & (NXCD - 1);
    const int idx = bid >> 3;
    const int chunk_base = (xcd < r) ? xcd * (q + 1) : r * (q + 1) + (xcd - r) * q;
    const int logical = chunk_base + idx;

    const int pk = order[logical];           // block-uniform -> scalar load
    const int v = ((unsigned)pk) >> 16;
    const int t = pk & 0xFFFF;
    const int j0 = threadIdx.x * 8;

    const float* col = W + v;

    // issue all 8 divergent loads, then fence so the compiler cannot sink
    // them into their uses (R5 lesson: VGPR=12 showed loads were serialized)
    float w0 = col[(size_t)(j0 + 0) * VOCAB];
    float w1 = col[(size_t)(j0 + 1) * VOCAB];
    float w2 = col[(size_t)(j0 + 2) * VOCAB];
    float w3 = col[(size_t)(j0 + 3) * VOCAB];
    float w4 = col[(size_t)(j0 + 4) * VOCAB];
    float w5 = col[(size_t)(j0 + 5) * VOCAB];
    float w6 = col[(size_t)(j0 + 6) * VOCAB];
    float w7 = col[(size_t)(j0 + 7) * VOCAB];
    __builtin_amdgcn_sched_barrier(0);

    const float4 blo = *reinterpret_cast<const float4*>(bias + j0);
    const float4 bhi = *reinterpret_cast<const float4*>(bias + j0 + 4);

    float4 o0, o1;
    o0.x = w0 + blo.x; o0.y = w1 + blo.y; o0.z = w2 + blo.z; o0.w = w3 + blo.w;
    o1.x = w4 + bhi.x; o1.y = w5 + bhi.y; o1.z = w6 + bhi.z; o1.w = w7 + bhi.w;

    float* dst = out + (size_t)t * DIM + j0;
    *reinterpret_cast<float4*>(dst)     = o0;
    *reinterpret_cast<float4*>(dst + 4) = o1;
}

// fallback (round-1 kernel) if workspace too small / n too large for packing
__global__ __launch_bounds__(256) void gather_direct_kernel(
    const int* __restrict__ x,
    const float* __restrict__ W,
    const float* __restrict__ bias,
    float* __restrict__ out)
{
    const int t = blockIdx.x;
    const int v = x[t];
    const int j0 = threadIdx.x * 4;
    float4 rr;
    rr.x = W[(size_t)(j0 + 0) * VOCAB + v];
    rr.y = W[(size_t)(j0 + 1) * VOCAB + v];
    rr.z = W[(size_t)(j0 + 2) * VOCAB + v];
    rr.w = W[(size_t)(j0 + 3) * VOCAB + v];
    const float4 bb = *reinterpret_cast<const float4*>(bias + j0);
    rr.x += bb.x; rr.y += bb.y; rr.z += bb.z; rr.w += bb.w;
    *reinterpret_cast<float4*>(out + (size_t)t * DIM + j0) = rr;
}

extern "C" void kernel_launch(void* const* d_in, const int* in_sizes, int n_in,
                              void* d_out, int out_size, void* d_ws, size_t ws_size,
                              hipStream_t stream) {
    const int*   x    = (const int*)d_in[0];
    const float* W    = (const float*)d_in[1];
    const float* bias = (const float*)d_in[2];
    float*       out  = (float*)d_out;

    const int n = in_sizes[0];           // 16384 tokens

    const size_t need = (size_t)(2 * NBUCK + n) * sizeof(int);
    if (ws_size < need || n > 65536) {   // packing uses 16 bits for token id
        gather_direct_kernel<<<n, 256, 0, stream>>>(x, W, bias, out);
        return;
    }

    int* counts = (int*)d_ws;            // [NBUCK]
    int* offs   = counts + NBUCK;        // [NBUCK]
    int* order  = offs + NBUCK;          // [n] packed (v<<16 | t)

    const int tb = 256;
    zero_counts_kernel<<<(NBUCK + tb - 1) / tb, tb, 0, stream>>>(counts, NBUCK);
    hist_kernel<<<(n + tb - 1) / tb, tb, 0, stream>>>(x, n, counts);
    scan_kernel<<<1, tb, 0, stream>>>(counts, offs);
    scatter_kernel<<<(n + tb - 1) / tb, tb, 0, stream>>>(x, n, offs, order);

    const int q = n / NXCD, r = n % NXCD;
    gather_sorted8_kernel<<<n, 128, 0, stream>>>(W, bias, order, out, q, r);
}